// Round 1
// baseline (3843.844 us; speedup 1.0000x reference)
//
#include <hip/hip_runtime.h>

#define NUM_GRAPHS 1024

// ---------------------------------------------------------------------------
// Kernel 1: edge scatter-add.  agg[dst] += x[src]  (4 fp32 features).
// 4 edges per thread via int4 index loads; unsafeAtomicAdd -> HW
// global_atomic_add_f32 (coarse-grained hipMalloc memory, so this is safe).
// ---------------------------------------------------------------------------
__global__ void edge_scatter_kernel(const float4* __restrict__ x,
                                    const int* __restrict__ src,
                                    const int* __restrict__ dst,
                                    float* __restrict__ agg,
                                    int E) {
    int t = blockIdx.x * blockDim.x + threadIdx.x;
    int e = t * 4;
    if (e + 3 < E) {
        int4 s = *(const int4*)(src + e);
        int4 d = *(const int4*)(dst + e);
        float4 xv;
        xv = x[s.x];
        unsafeAtomicAdd(&agg[(size_t)d.x * 4 + 0], xv.x);
        unsafeAtomicAdd(&agg[(size_t)d.x * 4 + 1], xv.y);
        unsafeAtomicAdd(&agg[(size_t)d.x * 4 + 2], xv.z);
        unsafeAtomicAdd(&agg[(size_t)d.x * 4 + 3], xv.w);
        xv = x[s.y];
        unsafeAtomicAdd(&agg[(size_t)d.y * 4 + 0], xv.x);
        unsafeAtomicAdd(&agg[(size_t)d.y * 4 + 1], xv.y);
        unsafeAtomicAdd(&agg[(size_t)d.y * 4 + 2], xv.z);
        unsafeAtomicAdd(&agg[(size_t)d.y * 4 + 3], xv.w);
        xv = x[s.z];
        unsafeAtomicAdd(&agg[(size_t)d.z * 4 + 0], xv.x);
        unsafeAtomicAdd(&agg[(size_t)d.z * 4 + 1], xv.y);
        unsafeAtomicAdd(&agg[(size_t)d.z * 4 + 2], xv.z);
        unsafeAtomicAdd(&agg[(size_t)d.z * 4 + 3], xv.w);
        xv = x[s.w];
        unsafeAtomicAdd(&agg[(size_t)d.w * 4 + 0], xv.x);
        unsafeAtomicAdd(&agg[(size_t)d.w * 4 + 1], xv.y);
        unsafeAtomicAdd(&agg[(size_t)d.w * 4 + 2], xv.z);
        unsafeAtomicAdd(&agg[(size_t)d.w * 4 + 3], xv.w);
    } else {
        for (int i = e; i < E; ++i) {
            int sv = src[i], dv = dst[i];
            float4 xv = x[sv];
            unsafeAtomicAdd(&agg[(size_t)dv * 4 + 0], xv.x);
            unsafeAtomicAdd(&agg[(size_t)dv * 4 + 1], xv.y);
            unsafeAtomicAdd(&agg[(size_t)dv * 4 + 2], xv.z);
            unsafeAtomicAdd(&agg[(size_t)dv * 4 + 3], xv.w);
        }
    }
}

// ---------------------------------------------------------------------------
// Kernel 2: per-node  h = (1+eps)*x + agg;  h = relu(relu(h@W1+b1)@W2+b2);
// then atomic accumulate into per-graph sums + counts.
// Weights read through uniform (scalar) loads — cached, negligible.
// ---------------------------------------------------------------------------
__global__ void node_mlp_pool_kernel(const float4* __restrict__ x,
                                     const float4* __restrict__ agg,
                                     const int* __restrict__ batch,
                                     const float* __restrict__ eps_p,
                                     const float* __restrict__ W1,
                                     const float* __restrict__ b1,
                                     const float* __restrict__ W2,
                                     const float* __restrict__ b2,
                                     float* __restrict__ gsum,
                                     float* __restrict__ gcnt,
                                     int N) {
    int i = blockIdx.x * blockDim.x + threadIdx.x;
    if (i >= N) return;

    float eps = eps_p[0];
    float4 xv = x[i];
    float4 av = agg[i];
    float h0 = (1.0f + eps) * xv.x + av.x;
    float h1 = (1.0f + eps) * xv.y + av.y;
    float h2 = (1.0f + eps) * xv.z + av.z;
    float h3 = (1.0f + eps) * xv.w + av.w;

    float t[16];
#pragma unroll
    for (int j = 0; j < 16; ++j) {
        float v = b1[j] + h0 * W1[j] + h1 * W1[16 + j] + h2 * W1[32 + j] + h3 * W1[48 + j];
        t[j] = v > 0.0f ? v : 0.0f;
    }

    float o[4];
#pragma unroll
    for (int j = 0; j < 4; ++j) {
        float v = b2[j];
#pragma unroll
        for (int k = 0; k < 16; ++k) v += t[k] * W2[k * 4 + j];
        o[j] = v > 0.0f ? v : 0.0f;
    }

    int g = batch[i];
    unsafeAtomicAdd(&gsum[(size_t)g * 4 + 0], o[0]);
    unsafeAtomicAdd(&gsum[(size_t)g * 4 + 1], o[1]);
    unsafeAtomicAdd(&gsum[(size_t)g * 4 + 2], o[2]);
    unsafeAtomicAdd(&gsum[(size_t)g * 4 + 3], o[3]);
    unsafeAtomicAdd(&gcnt[g], 1.0f);
}

// ---------------------------------------------------------------------------
// Kernel 3: pooled = sums / max(cnt,1);  out = log_softmax(pooled) per graph.
// ---------------------------------------------------------------------------
__global__ void pool_softmax_kernel(const float* __restrict__ gsum,
                                    const float* __restrict__ gcnt,
                                    float* __restrict__ out) {
    int g = blockIdx.x * blockDim.x + threadIdx.x;
    if (g >= NUM_GRAPHS) return;
    float c = gcnt[g];
    c = fmaxf(c, 1.0f);
    float p0 = gsum[g * 4 + 0] / c;
    float p1 = gsum[g * 4 + 1] / c;
    float p2 = gsum[g * 4 + 2] / c;
    float p3 = gsum[g * 4 + 3] / c;
    float m = fmaxf(fmaxf(p0, p1), fmaxf(p2, p3));
    float s = expf(p0 - m) + expf(p1 - m) + expf(p2 - m) + expf(p3 - m);
    float lse = m + logf(s);
    out[g * 4 + 0] = p0 - lse;
    out[g * 4 + 1] = p1 - lse;
    out[g * 4 + 2] = p2 - lse;
    out[g * 4 + 3] = p3 - lse;
}

extern "C" void kernel_launch(void* const* d_in, const int* in_sizes, int n_in,
                              void* d_out, int out_size, void* d_ws, size_t ws_size,
                              hipStream_t stream) {
    const float* x     = (const float*)d_in[0];
    const int*   ei    = (const int*)d_in[1];
    const int*   batch = (const int*)d_in[2];
    const float* eps   = (const float*)d_in[3];
    const float* W1    = (const float*)d_in[4];
    const float* b1    = (const float*)d_in[5];
    const float* W2    = (const float*)d_in[6];
    const float* b2    = (const float*)d_in[7];

    const int N = in_sizes[0] / 4;
    const int E = in_sizes[1] / 2;
    const int* src = ei;
    const int* dst = ei + (size_t)E;

    // Workspace layout: agg [N*4] | gsum [G*4] | gcnt [G]   (all fp32)
    float* agg  = (float*)d_ws;
    float* gsum = agg + (size_t)N * 4;
    float* gcnt = gsum + (size_t)NUM_GRAPHS * 4;
    size_t zero_bytes = ((size_t)N * 4 + (size_t)NUM_GRAPHS * 4 + NUM_GRAPHS) * sizeof(float);

    // ws is re-poisoned to 0xAA before every launch -> must zero each call.
    hipMemsetAsync(d_ws, 0, zero_bytes, stream);

    int e4 = (E + 3) / 4;  // threads for the edge kernel (4 edges/thread)
    edge_scatter_kernel<<<(e4 + 255) / 256, 256, 0, stream>>>(
        (const float4*)x, src, dst, agg, E);

    node_mlp_pool_kernel<<<(N + 255) / 256, 256, 0, stream>>>(
        (const float4*)x, (const float4*)agg, batch, eps, W1, b1, W2, b2,
        gsum, gcnt, N);

    pool_softmax_kernel<<<(NUM_GRAPHS + 255) / 256, 256, 0, stream>>>(
        gsum, gcnt, (float*)d_out);
}

// Round 2
// 926.913 us; speedup vs baseline: 4.1469x; 4.1469x over previous
//
#include <hip/hip_runtime.h>

#define NUM_GRAPHS 1024
#define BIN_BITS 10
#define BIN_SIZE (1 << BIN_BITS)     // 1024 nodes per bin
#define EB 16384                      // edges per binning block
#define BTHREADS 256
#define EPT (EB / BTHREADS)           // 64

// ---------------------------------------------------------------------------
// Fast path kernel A: init cursors + zero pool accumulators (1 block).
// ---------------------------------------------------------------------------
__global__ void init_kernel(int* __restrict__ cursor, float* __restrict__ gsum,
                            float* __restrict__ gcnt, int cap) {
    int t = threadIdx.x;  // 1024 threads
    if (t < 512) cursor[t] = t * cap;
    for (int j = t; j < NUM_GRAPHS * 4; j += 1024) gsum[j] = 0.0f;
    for (int j = t; j < NUM_GRAPHS; j += 1024) gcnt[j] = 0.0f;
}

// ---------------------------------------------------------------------------
// Fast path kernel B: bin edges by dst >> BIN_BITS into contiguous per-bin
// regions of `packed` ( (dst_local << 19) | src  — src < 2^19 guaranteed ).
// Per-block LDS histogram; ONE global atomic per (block,bin) to reserve space.
// ---------------------------------------------------------------------------
__global__ void bin_scatter(const int* __restrict__ src,
                            const int* __restrict__ dst,
                            int* __restrict__ packed,
                            int* __restrict__ cursor,
                            int E, int cap) {
    __shared__ int shist[512];
    __shared__ int sbase[512];
    const int t = threadIdx.x;
    const int b0 = blockIdx.x * EB;

    for (int j = t; j < 512; j += BTHREADS) shist[j] = 0;
    __syncthreads();

    // pass A: count
    for (int i = 0; i < EPT; ++i) {
        int e = b0 + i * BTHREADS + t;
        if (e < E) {
            int bin = ((unsigned)dst[e]) >> BIN_BITS;
            atomicAdd(&shist[bin], 1);
        }
    }
    __syncthreads();

    // reserve contiguous space per bin
    for (int j = t; j < 512; j += BTHREADS) {
        int c = shist[j];
        sbase[j] = (c > 0) ? atomicAdd(&cursor[j], c) : 0;
        shist[j] = 0;
    }
    __syncthreads();

    // pass B: place (chunk is L2-hot from pass A)
    for (int i = 0; i < EPT; ++i) {
        int e = b0 + i * BTHREADS + t;
        if (e < E) {
            int d = dst[e];
            int bin = ((unsigned)d) >> BIN_BITS;
            int lpos = atomicAdd(&shist[bin], 1);
            int pos = sbase[bin] + lpos;
            if (pos < (bin + 1) * cap) {   // overflow guard (>>20 sigma with this input)
                packed[pos] = ((d & (BIN_SIZE - 1)) << 19) | src[e];
            }
        }
    }
}

// ---------------------------------------------------------------------------
// Fast path kernel C: one block per bin; accumulate x[src] into a 20 KB LDS
// slice (stride 5 so dl*5+f covers all 32 banks), then PLAIN stores to agg.
// Zero global atomics.
// ---------------------------------------------------------------------------
__global__ void __launch_bounds__(512) bin_accum(const float4* __restrict__ x,
                                                 const int* __restrict__ packed,
                                                 const int* __restrict__ cursor,
                                                 float4* __restrict__ agg,
                                                 int N, int cap) {
    __shared__ float slice[BIN_SIZE * 5];   // 20 KB, padded stride
    const int bin = blockIdx.x;
    const int t = threadIdx.x;

    for (int j = t; j < BIN_SIZE * 5; j += 512) slice[j] = 0.0f;
    __syncthreads();

    int start = bin * cap;
    int end = cursor[bin];
    if (end > start + cap) end = start + cap;

    for (int e = start + t; e < end; e += 512) {
        int p = packed[e];
        int s = p & 0x7FFFF;
        int dl = ((unsigned)p) >> 19;
        float4 xv = x[s];
        atomicAdd(&slice[dl * 5 + 0], xv.x);
        atomicAdd(&slice[dl * 5 + 1], xv.y);
        atomicAdd(&slice[dl * 5 + 2], xv.z);
        atomicAdd(&slice[dl * 5 + 3], xv.w);
    }
    __syncthreads();

    int nbase = bin * BIN_SIZE;
    for (int j = t; j < BIN_SIZE; j += 512) {
        int n = nbase + j;
        if (n < N) {
            agg[n] = make_float4(slice[j * 5 + 0], slice[j * 5 + 1],
                                 slice[j * 5 + 2], slice[j * 5 + 3]);
        }
    }
}

// ---------------------------------------------------------------------------
// Fallback (ws too small): round-1 style direct atomic scatter.
// ---------------------------------------------------------------------------
__global__ void edge_scatter_kernel(const float4* __restrict__ x,
                                    const int* __restrict__ src,
                                    const int* __restrict__ dst,
                                    float* __restrict__ agg,
                                    int E) {
    int t = blockIdx.x * blockDim.x + threadIdx.x;
    int e = t * 4;
    if (e + 3 < E) {
        int4 s = *(const int4*)(src + e);
        int4 d = *(const int4*)(dst + e);
        float4 xv;
        xv = x[s.x];
        unsafeAtomicAdd(&agg[(size_t)d.x * 4 + 0], xv.x);
        unsafeAtomicAdd(&agg[(size_t)d.x * 4 + 1], xv.y);
        unsafeAtomicAdd(&agg[(size_t)d.x * 4 + 2], xv.z);
        unsafeAtomicAdd(&agg[(size_t)d.x * 4 + 3], xv.w);
        xv = x[s.y];
        unsafeAtomicAdd(&agg[(size_t)d.y * 4 + 0], xv.x);
        unsafeAtomicAdd(&agg[(size_t)d.y * 4 + 1], xv.y);
        unsafeAtomicAdd(&agg[(size_t)d.y * 4 + 2], xv.z);
        unsafeAtomicAdd(&agg[(size_t)d.y * 4 + 3], xv.w);
        xv = x[s.z];
        unsafeAtomicAdd(&agg[(size_t)d.z * 4 + 0], xv.x);
        unsafeAtomicAdd(&agg[(size_t)d.z * 4 + 1], xv.y);
        unsafeAtomicAdd(&agg[(size_t)d.z * 4 + 2], xv.z);
        unsafeAtomicAdd(&agg[(size_t)d.z * 4 + 3], xv.w);
        xv = x[s.w];
        unsafeAtomicAdd(&agg[(size_t)d.w * 4 + 0], xv.x);
        unsafeAtomicAdd(&agg[(size_t)d.w * 4 + 1], xv.y);
        unsafeAtomicAdd(&agg[(size_t)d.w * 4 + 2], xv.z);
        unsafeAtomicAdd(&agg[(size_t)d.w * 4 + 3], xv.w);
    } else {
        for (int i = e; i < E; ++i) {
            int sv = src[i], dv = dst[i];
            float4 xv = x[sv];
            unsafeAtomicAdd(&agg[(size_t)dv * 4 + 0], xv.x);
            unsafeAtomicAdd(&agg[(size_t)dv * 4 + 1], xv.y);
            unsafeAtomicAdd(&agg[(size_t)dv * 4 + 2], xv.z);
            unsafeAtomicAdd(&agg[(size_t)dv * 4 + 3], xv.w);
        }
    }
}

// ---------------------------------------------------------------------------
// Node MLP + pool. batch is SORTED -> waves are almost always graph-uniform:
// check uniformity, shuffle-reduce, one atomic set per wave (5 atomics)
// instead of 5 per lane.
// ---------------------------------------------------------------------------
__global__ void node_mlp_pool_kernel(const float4* __restrict__ x,
                                     const float4* __restrict__ agg,
                                     const int* __restrict__ batch,
                                     const float* __restrict__ eps_p,
                                     const float* __restrict__ W1,
                                     const float* __restrict__ b1,
                                     const float* __restrict__ W2,
                                     const float* __restrict__ b2,
                                     float* __restrict__ gsum,
                                     float* __restrict__ gcnt,
                                     int N) {
    int i = blockIdx.x * blockDim.x + threadIdx.x;
    bool valid = i < N;

    float o0 = 0.0f, o1 = 0.0f, o2 = 0.0f, o3 = 0.0f;
    int g = -1;
    if (valid) {
        float eps = eps_p[0];
        float4 xv = x[i];
        float4 av = agg[i];
        float h0 = (1.0f + eps) * xv.x + av.x;
        float h1 = (1.0f + eps) * xv.y + av.y;
        float h2 = (1.0f + eps) * xv.z + av.z;
        float h3 = (1.0f + eps) * xv.w + av.w;

        float tmp[16];
#pragma unroll
        for (int j = 0; j < 16; ++j) {
            float v = b1[j] + h0 * W1[j] + h1 * W1[16 + j] + h2 * W1[32 + j] + h3 * W1[48 + j];
            tmp[j] = v > 0.0f ? v : 0.0f;
        }
        float o[4];
#pragma unroll
        for (int j = 0; j < 4; ++j) {
            float v = b2[j];
#pragma unroll
            for (int k = 0; k < 16; ++k) v += tmp[k] * W2[k * 4 + j];
            o[j] = v > 0.0f ? v : 0.0f;
        }
        o0 = o[0]; o1 = o[1]; o2 = o[2]; o3 = o[3];
        g = batch[i];
    }

    int g0 = __shfl(g, 0);
    bool uni = __all(g == g0);
    if (uni && g0 >= 0) {
#pragma unroll
        for (int off = 32; off > 0; off >>= 1) {
            o0 += __shfl_down(o0, off);
            o1 += __shfl_down(o1, off);
            o2 += __shfl_down(o2, off);
            o3 += __shfl_down(o3, off);
        }
        if ((threadIdx.x & 63) == 0) {
            unsafeAtomicAdd(&gsum[(size_t)g0 * 4 + 0], o0);
            unsafeAtomicAdd(&gsum[(size_t)g0 * 4 + 1], o1);
            unsafeAtomicAdd(&gsum[(size_t)g0 * 4 + 2], o2);
            unsafeAtomicAdd(&gsum[(size_t)g0 * 4 + 3], o3);
            unsafeAtomicAdd(&gcnt[g0], 64.0f);
        }
    } else if (valid) {
        unsafeAtomicAdd(&gsum[(size_t)g * 4 + 0], o0);
        unsafeAtomicAdd(&gsum[(size_t)g * 4 + 1], o1);
        unsafeAtomicAdd(&gsum[(size_t)g * 4 + 2], o2);
        unsafeAtomicAdd(&gsum[(size_t)g * 4 + 3], o3);
        unsafeAtomicAdd(&gcnt[g], 1.0f);
    }
}

// ---------------------------------------------------------------------------
// pooled = sums / max(cnt,1); out = log_softmax per graph.
// ---------------------------------------------------------------------------
__global__ void pool_softmax_kernel(const float* __restrict__ gsum,
                                    const float* __restrict__ gcnt,
                                    float* __restrict__ out) {
    int g = blockIdx.x * blockDim.x + threadIdx.x;
    if (g >= NUM_GRAPHS) return;
    float c = fmaxf(gcnt[g], 1.0f);
    float p0 = gsum[g * 4 + 0] / c;
    float p1 = gsum[g * 4 + 1] / c;
    float p2 = gsum[g * 4 + 2] / c;
    float p3 = gsum[g * 4 + 3] / c;
    float m = fmaxf(fmaxf(p0, p1), fmaxf(p2, p3));
    float s = expf(p0 - m) + expf(p1 - m) + expf(p2 - m) + expf(p3 - m);
    float lse = m + logf(s);
    out[g * 4 + 0] = p0 - lse;
    out[g * 4 + 1] = p1 - lse;
    out[g * 4 + 2] = p2 - lse;
    out[g * 4 + 3] = p3 - lse;
}

extern "C" void kernel_launch(void* const* d_in, const int* in_sizes, int n_in,
                              void* d_out, int out_size, void* d_ws, size_t ws_size,
                              hipStream_t stream) {
    const float* x     = (const float*)d_in[0];
    const int*   ei    = (const int*)d_in[1];
    const int*   batch = (const int*)d_in[2];
    const float* eps   = (const float*)d_in[3];
    const float* W1    = (const float*)d_in[4];
    const float* b1    = (const float*)d_in[5];
    const float* W2    = (const float*)d_in[6];
    const float* b2    = (const float*)d_in[7];

    const int N = in_sizes[0] / 4;
    const int E = in_sizes[1] / 2;
    const int* src = ei;
    const int* dst = ei + (size_t)E;

    const int nb = (N + BIN_SIZE - 1) >> BIN_BITS;          // 489 for N=500K
    const int epb = (E + nb - 1) / nb;                       // mean edges/bin
    const int cap = epb + epb / 8 + 1024;                    // ~28 sigma headroom

    // Fast-path workspace layout (ints/floats, 4B):
    //   packed [nb*cap] | agg [N*4 f32] | cursor [512] | gsum [G*4] | gcnt [G]
    size_t packed_elems = ((size_t)nb * cap + 3) & ~(size_t)3;   // 16B-align next
    size_t need = (packed_elems + (size_t)N * 4 + 512 + NUM_GRAPHS * 4 + NUM_GRAPHS)
                  * sizeof(float);

    if (nb <= 512 && N < (1 << 19) && need <= ws_size) {
        // ---------------- fast path ----------------
        int*   packed = (int*)d_ws;
        float* agg    = (float*)d_ws + packed_elems;
        int*   cursor = (int*)(agg + (size_t)N * 4);
        float* gsum   = (float*)(cursor + 512);
        float* gcnt   = gsum + (size_t)NUM_GRAPHS * 4;

        init_kernel<<<1, 1024, 0, stream>>>(cursor, gsum, gcnt, cap);

        int nblocks_e = (E + EB - 1) / EB;
        bin_scatter<<<nblocks_e, BTHREADS, 0, stream>>>(src, dst, packed, cursor, E, cap);

        bin_accum<<<nb, 512, 0, stream>>>((const float4*)x, packed, cursor,
                                          (float4*)agg, N, cap);

        node_mlp_pool_kernel<<<(N + 255) / 256, 256, 0, stream>>>(
            (const float4*)x, (const float4*)agg, batch, eps, W1, b1, W2, b2,
            gsum, gcnt, N);

        pool_softmax_kernel<<<(NUM_GRAPHS + 255) / 256, 256, 0, stream>>>(
            gsum, gcnt, (float*)d_out);
    } else {
        // ---------------- fallback: round-1 atomic scatter ----------------
        float* agg  = (float*)d_ws;
        float* gsum = agg + (size_t)N * 4;
        float* gcnt = gsum + (size_t)NUM_GRAPHS * 4;
        size_t zero_bytes = ((size_t)N * 4 + NUM_GRAPHS * 5) * sizeof(float);
        hipMemsetAsync(d_ws, 0, zero_bytes, stream);

        int e4 = (E + 3) / 4;
        edge_scatter_kernel<<<(e4 + 255) / 256, 256, 0, stream>>>(
            (const float4*)x, src, dst, agg, E);

        node_mlp_pool_kernel<<<(N + 255) / 256, 256, 0, stream>>>(
            (const float4*)x, (const float4*)agg, batch, eps, W1, b1, W2, b2,
            gsum, gcnt, N);

        pool_softmax_kernel<<<(NUM_GRAPHS + 255) / 256, 256, 0, stream>>>(
            gsum, gcnt, (float*)d_out);
    }
}

// Round 3
// 650.719 us; speedup vs baseline: 5.9071x; 1.4244x over previous
//
#include <hip/hip_runtime.h>

#define NUM_GRAPHS 1024
#define BIN_BITS 10
#define BIN_SIZE (1 << BIN_BITS)      // 1024 nodes per bin
#define EB 8192                       // edges per binning block
#define STH 512                       // scatter threads (8 waves)
#define EPT 16                        // edges per thread in scatter (EB/STH)
#define ATH 1024                      // accum threads

// ---------------------------------------------------------------------------
// Init: cursors to bin bases, zero pool accumulators. (ws re-poisoned 0xAA
// before every timed launch.)
// ---------------------------------------------------------------------------
__global__ void init_kernel(int* __restrict__ cursor, float* __restrict__ gsum,
                            float* __restrict__ gcnt, int cap) {
    int t = threadIdx.x;  // 1024
    if (t < 512) cursor[t] = t * cap;
    for (int j = t; j < NUM_GRAPHS * 4; j += 1024) gsum[j] = 0.0f;
    for (int j = t; j < NUM_GRAPHS; j += 1024) gcnt[j] = 0.0f;
}

// ---------------------------------------------------------------------------
// bin_scatter v2: per-block counting sort of 8192 edges by dst-bin in LDS,
// then COALESCED flush of each bin segment to its reserved global region.
// packed = (dst_local << 19) | src   (src < 2^19, dst_local < 2^10).
// ---------------------------------------------------------------------------
__global__ void __launch_bounds__(STH) bin_scatter(const int* __restrict__ src,
                                                   const int* __restrict__ dst,
                                                   int* __restrict__ packed,
                                                   int* __restrict__ cursor,
                                                   int E, int cap, int nb) {
    __shared__ int shist[512];     // counts, then running offsets for placement
    __shared__ int sprefix[513];   // exclusive prefix of counts
    __shared__ int sgbase[512];    // global base per bin (this block's slot)
    __shared__ int spacked[EB];    // bin-sorted packed edges (32 KB)
    __shared__ int wsum[8];

    const int t = threadIdx.x;
    const int lane = t & 63;
    const int wave = t >> 6;
    const int b0 = blockIdx.x * EB;
    const int myBase = b0 + t * EPT;

    for (int j = t; j < 512; j += STH) shist[j] = 0;
    __syncthreads();

    // ---- pass A: count bins (vectorized dst loads) ----
    if (myBase + EPT <= E) {
#pragma unroll
        for (int v = 0; v < EPT / 4; ++v) {
            int4 d = *(const int4*)(dst + myBase + v * 4);
            atomicAdd(&shist[((unsigned)d.x) >> BIN_BITS], 1);
            atomicAdd(&shist[((unsigned)d.y) >> BIN_BITS], 1);
            atomicAdd(&shist[((unsigned)d.z) >> BIN_BITS], 1);
            atomicAdd(&shist[((unsigned)d.w) >> BIN_BITS], 1);
        }
    } else {
        for (int i = 0; i < EPT; ++i) {
            int e = myBase + i;
            if (e < E) atomicAdd(&shist[((unsigned)dst[e]) >> BIN_BITS], 1);
        }
    }
    __syncthreads();

    // ---- prefix scan of 512 counts (shfl within wave + cross-wave) ----
    {
        int v = shist[t];
        int inc = v;
#pragma unroll
        for (int off = 1; off < 64; off <<= 1) {
            int u = __shfl_up(inc, off);
            if (lane >= off) inc += u;
        }
        if (lane == 63) wsum[wave] = inc;
        __syncthreads();
        if (t == 0) {
            int acc = 0;
#pragma unroll
            for (int w = 0; w < 8; ++w) { int c = wsum[w]; wsum[w] = acc; acc += c; }
        }
        __syncthreads();
        int excl = inc - v + wsum[wave];       // exclusive prefix
        sprefix[t + 1] = excl + v;             // inclusive at t -> prefix[t+1]
        if (t == 0) sprefix[0] = 0;
        // reserve global space for this block's share of each bin
        if (t < nb && v > 0) sgbase[t] = atomicAdd(&cursor[t], v);
        shist[t] = 0;                          // reuse as running offset
    }
    __syncthreads();

    // ---- pass B: place edges bin-sorted into LDS ----
    if (myBase + EPT <= E) {
#pragma unroll
        for (int v = 0; v < EPT / 4; ++v) {
            int4 d = *(const int4*)(dst + myBase + v * 4);
            int4 s = *(const int4*)(src + myBase + v * 4);
            int bn, lp;
            bn = ((unsigned)d.x) >> BIN_BITS; lp = atomicAdd(&shist[bn], 1);
            spacked[sprefix[bn] + lp] = ((d.x & (BIN_SIZE - 1)) << 19) | s.x;
            bn = ((unsigned)d.y) >> BIN_BITS; lp = atomicAdd(&shist[bn], 1);
            spacked[sprefix[bn] + lp] = ((d.y & (BIN_SIZE - 1)) << 19) | s.y;
            bn = ((unsigned)d.z) >> BIN_BITS; lp = atomicAdd(&shist[bn], 1);
            spacked[sprefix[bn] + lp] = ((d.z & (BIN_SIZE - 1)) << 19) | s.z;
            bn = ((unsigned)d.w) >> BIN_BITS; lp = atomicAdd(&shist[bn], 1);
            spacked[sprefix[bn] + lp] = ((d.w & (BIN_SIZE - 1)) << 19) | s.w;
        }
    } else {
        for (int i = 0; i < EPT; ++i) {
            int e = myBase + i;
            if (e < E) {
                int d = dst[e];
                int bn = ((unsigned)d) >> BIN_BITS;
                int lp = atomicAdd(&shist[bn], 1);
                spacked[sprefix[bn] + lp] = ((d & (BIN_SIZE - 1)) << 19) | src[e];
            }
        }
    }
    __syncthreads();

    // ---- flush: bin segments -> contiguous global regions (coalesced) ----
    int cnt = sprefix[nb < 512 ? nb : 512];    // edges actually in this block
    int totE = E - b0; if (totE < 0) totE = 0;
    if (cnt > totE) cnt = totE;                // (defensive; equal in practice)
    for (int j = t; j < cnt; j += STH) {
        // binary search: bin b with sprefix[b] <= j < sprefix[b+1]
        int lo = 0, hi = nb;
        while (hi - lo > 1) {
            int mid = (lo + hi) >> 1;
            if (sprefix[mid] <= j) lo = mid; else hi = mid;
        }
        int pos = sgbase[lo] + (j - sprefix[lo]);
        if (pos < (lo + 1) * cap)              // overflow guard (~28 sigma)
            packed[pos] = spacked[j];
    }
}

// ---------------------------------------------------------------------------
// Fused: per-bin LDS accumulation of x[src]  +  node MLP  +  mean-pool reduce.
// One block per bin (1024 nodes), 1024 threads. agg never hits global memory.
// ---------------------------------------------------------------------------
__global__ void __launch_bounds__(ATH) bin_accum_mlp_pool(
        const float4* __restrict__ x,
        const int* __restrict__ packed,
        const int* __restrict__ cursor,
        const int* __restrict__ batch,
        const float* __restrict__ eps_p,
        const float* __restrict__ W1, const float* __restrict__ b1,
        const float* __restrict__ W2, const float* __restrict__ b2,
        float* __restrict__ gsum, float* __restrict__ gcnt,
        int N, int cap) {
    __shared__ float slice[BIN_SIZE * 5];   // 20 KB, stride-5 pad
    const int bin = blockIdx.x;
    const int t = threadIdx.x;

    for (int j = t; j < BIN_SIZE * 5; j += ATH) slice[j] = 0.0f;
    __syncthreads();

    int start = bin * cap;
    int end = cursor[bin];
    if (end > start + cap) end = start + cap;

    for (int e = start + t; e < end; e += ATH) {
        int p = packed[e];
        int s = p & 0x7FFFF;
        int dl = ((unsigned)p) >> 19;
        float4 xv = x[s];
        atomicAdd(&slice[dl * 5 + 0], xv.x);
        atomicAdd(&slice[dl * 5 + 1], xv.y);
        atomicAdd(&slice[dl * 5 + 2], xv.z);
        atomicAdd(&slice[dl * 5 + 3], xv.w);
    }
    __syncthreads();

    // ---- MLP + pool directly from the LDS slice ----
    int n = bin * BIN_SIZE + t;           // one node per thread
    bool valid = n < N;
    float o0 = 0.f, o1 = 0.f, o2 = 0.f, o3 = 0.f;
    int g = -1;
    if (valid) {
        float eps = eps_p[0];
        float4 xv = x[n];
        float h0 = (1.0f + eps) * xv.x + slice[t * 5 + 0];
        float h1 = (1.0f + eps) * xv.y + slice[t * 5 + 1];
        float h2 = (1.0f + eps) * xv.z + slice[t * 5 + 2];
        float h3 = (1.0f + eps) * xv.w + slice[t * 5 + 3];

        float tmp[16];
#pragma unroll
        for (int j = 0; j < 16; ++j) {
            float v = b1[j] + h0 * W1[j] + h1 * W1[16 + j] + h2 * W1[32 + j] + h3 * W1[48 + j];
            tmp[j] = v > 0.0f ? v : 0.0f;
        }
        float o[4];
#pragma unroll
        for (int j = 0; j < 4; ++j) {
            float v = b2[j];
#pragma unroll
            for (int k = 0; k < 16; ++k) v += tmp[k] * W2[k * 4 + j];
            o[j] = v > 0.0f ? v : 0.0f;
        }
        o0 = o[0]; o1 = o[1]; o2 = o[2]; o3 = o[3];
        g = batch[n];
    }

    // batch is sorted -> waves almost always graph-uniform
    int g0 = __shfl(g, 0);
    bool uni = __all(g == g0);
    if (uni && g0 >= 0) {
#pragma unroll
        for (int off = 32; off > 0; off >>= 1) {
            o0 += __shfl_down(o0, off);
            o1 += __shfl_down(o1, off);
            o2 += __shfl_down(o2, off);
            o3 += __shfl_down(o3, off);
        }
        if ((t & 63) == 0) {
            unsafeAtomicAdd(&gsum[(size_t)g0 * 4 + 0], o0);
            unsafeAtomicAdd(&gsum[(size_t)g0 * 4 + 1], o1);
            unsafeAtomicAdd(&gsum[(size_t)g0 * 4 + 2], o2);
            unsafeAtomicAdd(&gsum[(size_t)g0 * 4 + 3], o3);
            unsafeAtomicAdd(&gcnt[g0], 64.0f);
        }
    } else if (valid) {
        unsafeAtomicAdd(&gsum[(size_t)g * 4 + 0], o0);
        unsafeAtomicAdd(&gsum[(size_t)g * 4 + 1], o1);
        unsafeAtomicAdd(&gsum[(size_t)g * 4 + 2], o2);
        unsafeAtomicAdd(&gsum[(size_t)g * 4 + 3], o3);
        unsafeAtomicAdd(&gcnt[g], 1.0f);
    }
}

// ---------------------------------------------------------------------------
// pooled = sums / max(cnt,1); out = log_softmax per graph.
// ---------------------------------------------------------------------------
__global__ void pool_softmax_kernel(const float* __restrict__ gsum,
                                    const float* __restrict__ gcnt,
                                    float* __restrict__ out) {
    int g = blockIdx.x * blockDim.x + threadIdx.x;
    if (g >= NUM_GRAPHS) return;
    float c = fmaxf(gcnt[g], 1.0f);
    float p0 = gsum[g * 4 + 0] / c;
    float p1 = gsum[g * 4 + 1] / c;
    float p2 = gsum[g * 4 + 2] / c;
    float p3 = gsum[g * 4 + 3] / c;
    float m = fmaxf(fmaxf(p0, p1), fmaxf(p2, p3));
    float s = expf(p0 - m) + expf(p1 - m) + expf(p2 - m) + expf(p3 - m);
    float lse = m + logf(s);
    out[g * 4 + 0] = p0 - lse;
    out[g * 4 + 1] = p1 - lse;
    out[g * 4 + 2] = p2 - lse;
    out[g * 4 + 3] = p3 - lse;
}

// ---------------------------------------------------------------------------
// Fallback kernels (ws too small): round-1 style direct atomic scatter + MLP.
// ---------------------------------------------------------------------------
__global__ void edge_scatter_kernel(const float4* __restrict__ x,
                                    const int* __restrict__ src,
                                    const int* __restrict__ dst,
                                    float* __restrict__ agg,
                                    int E) {
    int t = blockIdx.x * blockDim.x + threadIdx.x;
    int e = t * 4;
    if (e + 3 < E) {
        int4 s = *(const int4*)(src + e);
        int4 d = *(const int4*)(dst + e);
        float4 xv;
        xv = x[s.x];
        unsafeAtomicAdd(&agg[(size_t)d.x * 4 + 0], xv.x);
        unsafeAtomicAdd(&agg[(size_t)d.x * 4 + 1], xv.y);
        unsafeAtomicAdd(&agg[(size_t)d.x * 4 + 2], xv.z);
        unsafeAtomicAdd(&agg[(size_t)d.x * 4 + 3], xv.w);
        xv = x[s.y];
        unsafeAtomicAdd(&agg[(size_t)d.y * 4 + 0], xv.x);
        unsafeAtomicAdd(&agg[(size_t)d.y * 4 + 1], xv.y);
        unsafeAtomicAdd(&agg[(size_t)d.y * 4 + 2], xv.z);
        unsafeAtomicAdd(&agg[(size_t)d.y * 4 + 3], xv.w);
        xv = x[s.z];
        unsafeAtomicAdd(&agg[(size_t)d.z * 4 + 0], xv.x);
        unsafeAtomicAdd(&agg[(size_t)d.z * 4 + 1], xv.y);
        unsafeAtomicAdd(&agg[(size_t)d.z * 4 + 2], xv.z);
        unsafeAtomicAdd(&agg[(size_t)d.z * 4 + 3], xv.w);
        xv = x[s.w];
        unsafeAtomicAdd(&agg[(size_t)d.w * 4 + 0], xv.x);
        unsafeAtomicAdd(&agg[(size_t)d.w * 4 + 1], xv.y);
        unsafeAtomicAdd(&agg[(size_t)d.w * 4 + 2], xv.z);
        unsafeAtomicAdd(&agg[(size_t)d.w * 4 + 3], xv.w);
    } else {
        for (int i = e; i < E; ++i) {
            int sv = src[i], dv = dst[i];
            float4 xv = x[sv];
            unsafeAtomicAdd(&agg[(size_t)dv * 4 + 0], xv.x);
            unsafeAtomicAdd(&agg[(size_t)dv * 4 + 1], xv.y);
            unsafeAtomicAdd(&agg[(size_t)dv * 4 + 2], xv.z);
            unsafeAtomicAdd(&agg[(size_t)dv * 4 + 3], xv.w);
        }
    }
}

__global__ void node_mlp_pool_kernel(const float4* __restrict__ x,
                                     const float4* __restrict__ agg,
                                     const int* __restrict__ batch,
                                     const float* __restrict__ eps_p,
                                     const float* __restrict__ W1,
                                     const float* __restrict__ b1,
                                     const float* __restrict__ W2,
                                     const float* __restrict__ b2,
                                     float* __restrict__ gsum,
                                     float* __restrict__ gcnt,
                                     int N) {
    int i = blockIdx.x * blockDim.x + threadIdx.x;
    bool valid = i < N;
    float o0 = 0.f, o1 = 0.f, o2 = 0.f, o3 = 0.f;
    int g = -1;
    if (valid) {
        float eps = eps_p[0];
        float4 xv = x[i];
        float4 av = agg[i];
        float h0 = (1.0f + eps) * xv.x + av.x;
        float h1 = (1.0f + eps) * xv.y + av.y;
        float h2 = (1.0f + eps) * xv.z + av.z;
        float h3 = (1.0f + eps) * xv.w + av.w;
        float tmp[16];
#pragma unroll
        for (int j = 0; j < 16; ++j) {
            float v = b1[j] + h0 * W1[j] + h1 * W1[16 + j] + h2 * W1[32 + j] + h3 * W1[48 + j];
            tmp[j] = v > 0.0f ? v : 0.0f;
        }
        float o[4];
#pragma unroll
        for (int j = 0; j < 4; ++j) {
            float v = b2[j];
#pragma unroll
            for (int k = 0; k < 16; ++k) v += tmp[k] * W2[k * 4 + j];
            o[j] = v > 0.0f ? v : 0.0f;
        }
        o0 = o[0]; o1 = o[1]; o2 = o[2]; o3 = o[3];
        g = batch[i];
    }
    int g0 = __shfl(g, 0);
    bool uni = __all(g == g0);
    if (uni && g0 >= 0) {
#pragma unroll
        for (int off = 32; off > 0; off >>= 1) {
            o0 += __shfl_down(o0, off);
            o1 += __shfl_down(o1, off);
            o2 += __shfl_down(o2, off);
            o3 += __shfl_down(o3, off);
        }
        if ((threadIdx.x & 63) == 0) {
            unsafeAtomicAdd(&gsum[(size_t)g0 * 4 + 0], o0);
            unsafeAtomicAdd(&gsum[(size_t)g0 * 4 + 1], o1);
            unsafeAtomicAdd(&gsum[(size_t)g0 * 4 + 2], o2);
            unsafeAtomicAdd(&gsum[(size_t)g0 * 4 + 3], o3);
            unsafeAtomicAdd(&gcnt[g0], 64.0f);
        }
    } else if (valid) {
        unsafeAtomicAdd(&gsum[(size_t)g * 4 + 0], o0);
        unsafeAtomicAdd(&gsum[(size_t)g * 4 + 1], o1);
        unsafeAtomicAdd(&gsum[(size_t)g * 4 + 2], o2);
        unsafeAtomicAdd(&gsum[(size_t)g * 4 + 3], o3);
        unsafeAtomicAdd(&gcnt[g], 1.0f);
    }
}

extern "C" void kernel_launch(void* const* d_in, const int* in_sizes, int n_in,
                              void* d_out, int out_size, void* d_ws, size_t ws_size,
                              hipStream_t stream) {
    const float* x     = (const float*)d_in[0];
    const int*   ei    = (const int*)d_in[1];
    const int*   batch = (const int*)d_in[2];
    const float* eps   = (const float*)d_in[3];
    const float* W1    = (const float*)d_in[4];
    const float* b1    = (const float*)d_in[5];
    const float* W2    = (const float*)d_in[6];
    const float* b2    = (const float*)d_in[7];

    const int N = in_sizes[0] / 4;
    const int E = in_sizes[1] / 2;
    const int* src = ei;
    const int* dst = ei + (size_t)E;

    const int nb = (N + BIN_SIZE - 1) >> BIN_BITS;   // 489 for N=500K
    const int epb = (E + nb - 1) / nb;
    const int cap = epb + epb / 8 + 1024;            // ~28 sigma headroom

    // Fast-path ws layout: packed [nb*cap] | cursor [512] | gsum [G*4] | gcnt [G]
    size_t packed_elems = ((size_t)nb * cap + 3) & ~(size_t)3;
    size_t need = (packed_elems + 512 + NUM_GRAPHS * 4 + NUM_GRAPHS) * sizeof(float);

    if (nb <= 512 && N < (1 << 19) && need <= ws_size) {
        int*   packed = (int*)d_ws;
        int*   cursor = (int*)d_ws + packed_elems;
        float* gsum   = (float*)(cursor + 512);
        float* gcnt   = gsum + (size_t)NUM_GRAPHS * 4;

        init_kernel<<<1, 1024, 0, stream>>>(cursor, gsum, gcnt, cap);

        int nblocks_e = (E + EB - 1) / EB;
        bin_scatter<<<nblocks_e, STH, 0, stream>>>(src, dst, packed, cursor, E, cap, nb);

        bin_accum_mlp_pool<<<nb, ATH, 0, stream>>>(
            (const float4*)x, packed, cursor, batch, eps, W1, b1, W2, b2,
            gsum, gcnt, N, cap);

        pool_softmax_kernel<<<(NUM_GRAPHS + 255) / 256, 256, 0, stream>>>(
            gsum, gcnt, (float*)d_out);
    } else {
        float* agg  = (float*)d_ws;
        float* gsum = agg + (size_t)N * 4;
        float* gcnt = gsum + (size_t)NUM_GRAPHS * 4;
        size_t zero_bytes = ((size_t)N * 4 + NUM_GRAPHS * 5) * sizeof(float);
        hipMemsetAsync(d_ws, 0, zero_bytes, stream);

        int e4 = (E + 3) / 4;
        edge_scatter_kernel<<<(e4 + 255) / 256, 256, 0, stream>>>(
            (const float4*)x, src, dst, agg, E);

        node_mlp_pool_kernel<<<(N + 255) / 256, 256, 0, stream>>>(
            (const float4*)x, (const float4*)agg, batch, eps, W1, b1, W2, b2,
            gsum, gcnt, N);

        pool_softmax_kernel<<<(NUM_GRAPHS + 255) / 256, 256, 0, stream>>>(
            gsum, gcnt, (float*)d_out);
    }
}